// Round 7
// baseline (617.118 us; speedup 1.0000x reference)
//
#include <hip/hip_runtime.h>
#include <hip/hip_cooperative_groups.h>

namespace cg = cooperative_groups;

// Shape: N=300000 src nodes, K=6 neighbors, F=64 features, N_up=75000 selections.
// Single cooperative kernel, three phases separated by grid.sync():
//   mark   : cnt[sel[u]] = 0. No memset needed — harness poisons ws with 0xAA,
//            and 0xAAAAAAAA is already negative (sentinel). Unmarked dests with
//            garbage cnt>=0 only cause harmless never-read table writes.
//   build  : 4 edges/thread (int4/float4 coalesced), plain cnt pre-check kills
//            78% of atomics; slot = atomicAdd(&cnt[idx],1); store (src, wn).
//   gather : quarter-wave float4 — 16 lanes x 16B = one 256B feature row, so
//            each load instruction covers 4 rows (4x MLP per issue slot).
//            Persistent grid-stride keeps waves resident.
// CAP=32: 256B-aligned rows; P(in-degree>=32 | ~Poisson(6)) < 1e-13.

#define KNB 6
#define FDIM 64
#define CAP 32
#define EB 4

// ---------------- phase bodies (shared by fused + fallback paths) -----------

__device__ __forceinline__ void phase_mark(const int* __restrict__ sel,
                                           int* __restrict__ cnt,
                                           int Nup, int tid, int nthreads) {
    for (int u = tid; u < Nup; u += nthreads) cnt[sel[u]] = 0;
}

__device__ __forceinline__ void phase_build(const float* __restrict__ weight,
                                            const float* __restrict__ nweights,
                                            const int*   __restrict__ nidx,
                                            int* __restrict__ cnt,
                                            int2* __restrict__ table,
                                            int E, int tid, int nthreads) {
    const int nchunks = E / EB;  // E = 1.8M divisible by 4
    for (int ch = tid; ch < nchunks; ch += nthreads) {
        const int e0 = ch * EB;
        const int4   i4 = *(const int4*)(nidx + e0);
        const float4 n4 = *(const float4*)(nweights + e0);
        const int   idx[EB] = {i4.x, i4.y, i4.z, i4.w};
        const float nw [EB] = {n4.x, n4.y, n4.z, n4.w};
        int c[EB];
        #pragma unroll
        for (int j = 0; j < EB; ++j)
            c[j] = (idx[j] >= 0) ? cnt[idx[j]] : -1;
        #pragma unroll
        for (int j = 0; j < EB; ++j) {
            if (c[j] >= 0) {  // marked (cnt monotone non-negative iff marked)
                const int slot = atomicAdd(&cnt[idx[j]], 1);
                if (slot < CAP) {
                    const int e = e0 + j;
                    const int i = e / KNB;
                    float w = weight[i];
                    w = w > 0.0f ? w : 0.0f;
                    table[(size_t)idx[j] * CAP + slot] =
                        make_int2(i, __float_as_int(nw[j] * w));
                }
            }
        }
    }
}

__device__ __forceinline__ void phase_gather(const float* __restrict__ features,
                                             const int*   __restrict__ sel,
                                             const int*   __restrict__ cnt,
                                             const int2*  __restrict__ table,
                                             float* __restrict__ out,
                                             int Nup, int tid, int nthreads) {
    const int lane = tid & 63;
    const int q    = lane >> 4;   // quarter 0..3 -> dest within group
    const int l    = lane & 15;   // lane in quarter -> float4 chunk of row
    const int wid  = tid >> 6;
    const int nwv  = nthreads >> 6;
    const int ngroups = (Nup + 3) >> 2;
    const float4* feat4 = (const float4*)features;

    for (int g = wid; g < ngroups; g += nwv) {
        const int u  = g * 4 + q;
        const int uc = (u < Nup) ? u : (Nup - 1);
        const int s  = sel[uc];
        int c = cnt[s];
        c = c < 0 ? 0 : (c > CAP ? CAP : c);

        const int4* row = (const int4*)(table + (size_t)s * CAP);  // 256B-aligned
        const int4 t0 = row[0], t1 = row[1], t2 = row[2], t3 = row[3];

        int   sj[8];
        float wj[8];
        sj[0] = t0.x; wj[0] = __int_as_float(t0.y);
        sj[1] = t0.z; wj[1] = __int_as_float(t0.w);
        sj[2] = t1.x; wj[2] = __int_as_float(t1.y);
        sj[3] = t1.z; wj[3] = __int_as_float(t1.w);
        sj[4] = t2.x; wj[4] = __int_as_float(t2.y);
        sj[5] = t2.z; wj[5] = __int_as_float(t2.w);
        sj[6] = t3.x; wj[6] = __int_as_float(t3.y);
        sj[7] = t3.z; wj[7] = __int_as_float(t3.w);
        #pragma unroll
        for (int j = 0; j < 8; ++j) {  // predicate-safe clamp
            const bool v = j < c;
            sj[j] = v ? sj[j] : 0;
            wj[j] = v ? wj[j] : 0.0f;
        }

        // 8 independent float4 loads; each instruction covers 4 rows (1KB).
        float4 fv[8];
        #pragma unroll
        for (int j = 0; j < 8; ++j)
            fv[j] = feat4[(size_t)sj[j] * 16 + l];

        float4 acc = make_float4(0.f, 0.f, 0.f, 0.f);
        float dsum = 0.f;
        #pragma unroll
        for (int j = 0; j < 8; ++j) {
            acc.x = fmaf(wj[j], fv[j].x, acc.x);
            acc.y = fmaf(wj[j], fv[j].y, acc.y);
            acc.z = fmaf(wj[j], fv[j].z, acc.z);
            acc.w = fmaf(wj[j], fv[j].w, acc.w);
            dsum += wj[j];
        }
        // Rare tail: in-degree > 8 (~15% of rows; >16 ~0.1%).
        for (int j = 8; j < c; ++j) {
            const int2 tt = table[(size_t)s * CAP + j];
            const float wn = __int_as_float(tt.y);
            const float4 fx = feat4[(size_t)tt.x * 16 + l];
            acc.x = fmaf(wn, fx.x, acc.x);
            acc.y = fmaf(wn, fx.y, acc.y);
            acc.z = fmaf(wn, fx.z, acc.z);
            acc.w = fmaf(wn, fx.w, acc.w);
            dsum += wn;
        }

        if (u < Nup) {
            const float d = dsum + 0.001f;  // dsum>=0 so d>=0.001 (matches ref)
            ((float4*)out)[(size_t)u * 16 + l] =
                make_float4(acc.x / d, acc.y / d, acc.z / d, acc.w / d);
        }
    }
}

// ---------------- fused cooperative kernel ----------------------------------

__global__ __launch_bounds__(256, 4)
void fused_kernel(const float* __restrict__ features,
                  const float* __restrict__ weight,
                  const float* __restrict__ nweights,
                  const int*   __restrict__ nidx,
                  const int*   __restrict__ sel,
                  int* cnt, int2* table, float* out,
                  int Nup, int E) {
    cg::grid_group grid = cg::this_grid();
    const int tid = blockIdx.x * blockDim.x + threadIdx.x;
    const int nthreads = gridDim.x * blockDim.x;

    phase_mark(sel, cnt, Nup, tid, nthreads);
    __threadfence();
    grid.sync();

    phase_build(weight, nweights, nidx, cnt, table, E, tid, nthreads);
    __threadfence();
    grid.sync();

    phase_gather(features, sel, cnt, table, out, Nup, tid, nthreads);
}

// ---------------- fallback separate kernels ---------------------------------

__global__ void mark_kernel(const int* sel, int* cnt, int Nup) {
    phase_mark(sel, cnt, Nup,
               blockIdx.x * blockDim.x + threadIdx.x, gridDim.x * blockDim.x);
}
__global__ void build_kernel(const float* weight, const float* nweights,
                             const int* nidx, int* cnt, int2* table, int E) {
    phase_build(weight, nweights, nidx, cnt, table, E,
                blockIdx.x * blockDim.x + threadIdx.x, gridDim.x * blockDim.x);
}
__global__ void gather_kernel(const float* features, const int* sel,
                              const int* cnt, const int2* table,
                              float* out, int Nup) {
    phase_gather(features, sel, cnt, table, out, Nup,
                 blockIdx.x * blockDim.x + threadIdx.x, gridDim.x * blockDim.x);
}

extern "C" void kernel_launch(void* const* d_in, const int* in_sizes, int n_in,
                              void* d_out, int out_size, void* d_ws, size_t ws_size,
                              hipStream_t stream) {
    const float* features = (const float*)d_in[0];  // N*64
    const float* weight   = (const float*)d_in[1];  // N
    const float* nweights = (const float*)d_in[2];  // N*6
    const int*   nidx     = (const int*)d_in[3];    // N*6
    const int*   sel      = (const int*)d_in[4];    // N_up

    const int N   = in_sizes[1];
    const int Nup = in_sizes[4];
    int       E   = N * KNB;

    // ws layout: cnt[N] | table[N*CAP] (int2) -> 1.2 MB + 76.8 MB
    int*  cnt   = (int*)d_ws;
    int2* table = (int2*)(cnt + N);
    float* outp = (float*)d_out;

    const int T = 256;

    // Cooperative path: persistent grid, clamped to co-resident capacity.
    int maxb = 0;
    hipError_t oerr = hipOccupancyMaxActiveBlocksPerMultiprocessor(
        &maxb, (const void*)fused_kernel, T, 0);
    int blocks = 1024;
    if (oerr == hipSuccess && maxb > 0) {
        const int capb = maxb * 256;  // 256 CUs on MI355X
        if (blocks > capb) blocks = capb;
    }

    void* args[] = {(void*)&features, (void*)&weight, (void*)&nweights,
                    (void*)&nidx, (void*)&sel, (void*)&cnt, (void*)&table,
                    (void*)&outp, (void*)&Nup, (void*)&E};
    hipError_t err = hipLaunchCooperativeKernel(
        (const void*)fused_kernel, dim3(blocks), dim3(T), args, 0, stream);

    if (err != hipSuccess) {
        // Fallback: three ordinary dispatches (same phase bodies).
        mark_kernel <<<(Nup + T - 1) / T, T, 0, stream>>>(sel, cnt, Nup);
        const int nthreads_build = E / EB;
        build_kernel<<<(nthreads_build + T - 1) / T, T, 0, stream>>>(
            weight, nweights, nidx, cnt, table, E);
        const int waves  = (Nup + 3) / 4;
        const int blocksg = (waves + 3) / 4;  // 4 waves per block
        gather_kernel<<<blocksg, T, 0, stream>>>(features, sel, cnt, table,
                                                 outp, Nup);
    }
}

// Round 8
// 184.196 us; speedup vs baseline: 3.3503x; 3.3503x over previous
//
#include <hip/hip_runtime.h>

// Shape: N=300000 src nodes, K=6 neighbors, F=64 features, N_up=75000 selections.
// Three ordinary dispatches (cooperative fusion measured 2.5x WORSE — grid.sync
// across 8 XCDs serializes everything; round-7 post-mortem).
//   mark   : cnt[sel[u]] = 0. No memset — harness poisons ws to 0xAA each call
//            and 0xAAAAAAAA is already a negative sentinel (validated round 7).
//   build  : 4 edges/thread (int4/float4 coalesced), plain cnt pre-check kills
//            78% of atomics; slot = atomicAdd(&cnt[idx],1); store (src, wn).
//   gather : quarter-wave float4, 8 dests/wave — 16 independent 1KB feature
//            loads + 8 table int4 loads in flight per wave (2x round 6's MLP).
// CAP=32: 256B-aligned rows; P(in-degree>=32 | ~Poisson(6)) < 1e-13.

#define KNB 6
#define FDIM 64
#define CAP 32
#define EB 4

__global__ void mark_kernel(const int* __restrict__ sel,
                            int* __restrict__ cnt,
                            int Nup) {
    const int u = blockIdx.x * blockDim.x + threadIdx.x;
    if (u < Nup) cnt[sel[u]] = 0;
}

__global__ void build_kernel(const float* __restrict__ weight,
                             const float* __restrict__ nweights,
                             const int*   __restrict__ nidx,
                             int* __restrict__ cnt,
                             int2* __restrict__ table,
                             int E) {
    const int t  = blockIdx.x * blockDim.x + threadIdx.x;
    const int e0 = t * EB;
    if (e0 >= E) return;

    const int4   i4 = *(const int4*)(nidx + e0);      // E divisible by 4
    const float4 n4 = *(const float4*)(nweights + e0);
    const int   idx[EB] = {i4.x, i4.y, i4.z, i4.w};
    const float nw [EB] = {n4.x, n4.y, n4.z, n4.w};

    int c[EB];
    #pragma unroll
    for (int j = 0; j < EB; ++j)
        c[j] = (idx[j] >= 0) ? cnt[idx[j]] : -1;

    #pragma unroll
    for (int j = 0; j < EB; ++j) {
        if (c[j] >= 0) {  // marked dest (cnt monotone non-negative iff marked)
            const int slot = atomicAdd(&cnt[idx[j]], 1);
            if (slot < CAP) {
                const int e = e0 + j;
                const int i = e / KNB;
                float w = weight[i];
                w = w > 0.0f ? w : 0.0f;
                table[(size_t)idx[j] * CAP + slot] =
                    make_int2(i, __float_as_int(nw[j] * w));
            }
        }
    }
}

// Quarter-wave gather, 8 destinations per wave:
//   lane = 16*q + l ; quarter q handles dests u0+q and u0+4+q; lane chunk l
//   covers bytes [16l,16l+16) of the 256B feature row.
__global__ void gather_kernel(const float* __restrict__ features,
                              const int*   __restrict__ sel,
                              const int*   __restrict__ cnt,
                              const int2*  __restrict__ table,
                              float* __restrict__ out,
                              int Nup) {
    const int wave = blockIdx.x * (blockDim.x >> 6) + (threadIdx.x >> 6);
    const int lane = threadIdx.x & 63;
    const int q    = lane >> 4;
    const int l    = lane & 15;
    const int u0   = wave * 8;
    if (u0 >= Nup) return;

    const float4* feat4 = (const float4*)features;

    const int uA = u0 + q;
    const int uB = u0 + 4 + q;
    const int uAc = (uA < Nup) ? uA : (Nup - 1);
    const int uBc = (uB < Nup) ? uB : (Nup - 1);

    // Level 1: sel (2 independent loads)
    const int sA = sel[uAc];
    const int sB = sel[uBc];
    // Level 2: cnt + table rows (10 independent loads)
    int cA = cnt[sA], cB = cnt[sB];
    const int4* rowA = (const int4*)(table + (size_t)sA * CAP);
    const int4* rowB = (const int4*)(table + (size_t)sB * CAP);
    int4 tA[4], tB[4];
    #pragma unroll
    for (int p = 0; p < 4; ++p) { tA[p] = rowA[p]; tB[p] = rowB[p]; }

    cA = cA < 0 ? 0 : (cA > CAP ? CAP : cA);
    cB = cB < 0 ? 0 : (cB > CAP ? CAP : cB);

    int   srcA[8], srcB[8];
    float wnA[8],  wnB[8];
    #pragma unroll
    for (int p = 0; p < 4; ++p) {
        srcA[2*p]   = tA[p].x; wnA[2*p]   = __int_as_float(tA[p].y);
        srcA[2*p+1] = tA[p].z; wnA[2*p+1] = __int_as_float(tA[p].w);
        srcB[2*p]   = tB[p].x; wnB[2*p]   = __int_as_float(tB[p].y);
        srcB[2*p+1] = tB[p].z; wnB[2*p+1] = __int_as_float(tB[p].w);
    }
    #pragma unroll
    for (int j = 0; j < 8; ++j) {  // predicate-safe clamp (no extra HBM: row 0)
        const bool vA = j < cA, vB = j < cB;
        srcA[j] = vA ? srcA[j] : 0;  wnA[j] = vA ? wnA[j] : 0.0f;
        srcB[j] = vB ? srcB[j] : 0;  wnB[j] = vB ? wnB[j] : 0.0f;
    }

    // Level 3: 16 independent float4 loads (each instruction = 4 rows, 1KB)
    float4 fA[8], fB[8];
    #pragma unroll
    for (int j = 0; j < 8; ++j) fA[j] = feat4[(size_t)srcA[j] * 16 + l];
    #pragma unroll
    for (int j = 0; j < 8; ++j) fB[j] = feat4[(size_t)srcB[j] * 16 + l];

    float4 aA = make_float4(0.f,0.f,0.f,0.f), aB = make_float4(0.f,0.f,0.f,0.f);
    float dA = 0.f, dB = 0.f;
    #pragma unroll
    for (int j = 0; j < 8; ++j) {
        aA.x = fmaf(wnA[j], fA[j].x, aA.x); aA.y = fmaf(wnA[j], fA[j].y, aA.y);
        aA.z = fmaf(wnA[j], fA[j].z, aA.z); aA.w = fmaf(wnA[j], fA[j].w, aA.w);
        dA += wnA[j];
        aB.x = fmaf(wnB[j], fB[j].x, aB.x); aB.y = fmaf(wnB[j], fB[j].y, aB.y);
        aB.z = fmaf(wnB[j], fB[j].z, aB.z); aB.w = fmaf(wnB[j], fB[j].w, aB.w);
        dB += wnB[j];
    }
    // Rare tails (in-degree > 8, ~15% of rows; >16 ~0.1%).
    for (int j = 8; j < cA; ++j) {
        const int2 tt = table[(size_t)sA * CAP + j];
        const float wn = __int_as_float(tt.y);
        const float4 fx = feat4[(size_t)tt.x * 16 + l];
        aA.x = fmaf(wn, fx.x, aA.x); aA.y = fmaf(wn, fx.y, aA.y);
        aA.z = fmaf(wn, fx.z, aA.z); aA.w = fmaf(wn, fx.w, aA.w);
        dA += wn;
    }
    for (int j = 8; j < cB; ++j) {
        const int2 tt = table[(size_t)sB * CAP + j];
        const float wn = __int_as_float(tt.y);
        const float4 fx = feat4[(size_t)tt.x * 16 + l];
        aB.x = fmaf(wn, fx.x, aB.x); aB.y = fmaf(wn, fx.y, aB.y);
        aB.z = fmaf(wn, fx.z, aB.z); aB.w = fmaf(wn, fx.w, aB.w);
        dB += wn;
    }

    if (uA < Nup) {
        const float d = dA + 0.001f;  // dsum>=0 so d>=0.001 (matches ref)
        ((float4*)out)[(size_t)uA * 16 + l] =
            make_float4(aA.x/d, aA.y/d, aA.z/d, aA.w/d);
    }
    if (uB < Nup) {
        const float d = dB + 0.001f;
        ((float4*)out)[(size_t)uB * 16 + l] =
            make_float4(aB.x/d, aB.y/d, aB.z/d, aB.w/d);
    }
}

extern "C" void kernel_launch(void* const* d_in, const int* in_sizes, int n_in,
                              void* d_out, int out_size, void* d_ws, size_t ws_size,
                              hipStream_t stream) {
    const float* features = (const float*)d_in[0];  // N*64
    const float* weight   = (const float*)d_in[1];  // N
    const float* nweights = (const float*)d_in[2];  // N*6
    const int*   nidx     = (const int*)d_in[3];    // N*6
    const int*   sel      = (const int*)d_in[4];    // N_up

    const int N   = in_sizes[1];
    const int Nup = in_sizes[4];
    const int E   = N * KNB;

    // ws layout: cnt[N] | table[N*CAP] (int2) -> 1.2 MB + 76.8 MB
    int*  cnt   = (int*)d_ws;
    int2* table = (int2*)(cnt + N);

    const int T = 256;
    mark_kernel<<<(Nup + T - 1) / T, T, 0, stream>>>(sel, cnt, Nup);

    const int nthreads_build = E / EB;
    build_kernel<<<(nthreads_build + T - 1) / T, T, 0, stream>>>(
        weight, nweights, nidx, cnt, table, E);

    const int waves  = (Nup + 7) / 8;
    const int wpb    = T / 64;                 // 4 waves per block
    const int blocks = (waves + wpb - 1) / wpb;
    gather_kernel<<<blocks, T, 0, stream>>>(features, sel, cnt, table,
                                            (float*)d_out, Nup);
}